// Round 5
// baseline (578.628 us; speedup 1.0000x reference)
//
#include <hip/hip_runtime.h>
#include <stdint.h>

// ---------------------------------------------------------------------------
// TopkQuantLayer: out = scatter(quant(top 25% by |x|)), n = 32M fp32.
// R4: MLP fix for all streaming passes. R3 post-mortem: gather was limited by
// a per-thread dependency chain (1 load -> 4 sequential variable-trip LDS
// probe loops), not barriers/atomics — VALUBusy 9%, eff. read 1 TB/s. Now:
// 4x unrolled independent uint4 loads per iteration in hist13/hist9/gather/
// out, and gather uses a batched two-phase probe (16 hashes -> 16 independent
// first-probe ds_reads -> rare fallback loop) so the common case has no
// dependent LDS chain and no branches.
// ---------------------------------------------------------------------------

#define H13BINS   8192
#define P13       256      // hist13 grid (partial count)
#define P9        256      // hist9 grid
#define NSLOT_MAX 40
#define SLOT_CAP  8192
#define MAX_TIES  1024
#define GSL       16       // slots per scan-group in k_sel9
#define HTAB_SZ   2048
#define GATHER_BLOCKS 2048
#define OUT_BLOCKS    2048

// ctl word offsets
#define CTL_ASTAR13   0
#define CTL_RRA       1
#define CTL_ABOVEA    2
#define CTL_NS13      3
#define CTL_POSAB13   4
#define CTL_TKEY      5
#define CTL_NTIES     6
#define CTL_RR2       7
#define CTL_CNTABOVE  8
#define CTL_POSABOVE  9
#define CTL_NSLOT     10
#define CTL_A21       11
#define CTL_S13BIN    16   // 40
#define CTL_C13SLOT   56   // 32
#define CTL_C13RES    88   // 32
#define CTL_SLOTBIN   120  // 40 (gather bin22 list)
#define CTL_CANDSLOT  160  // 32
#define CTL_CANDRES   192  // 32
#define CTL_BND       224  // 7
#define CTL_MN        232  // 8
#define CTL_MX        240  // 8
#define CTL_STEP      248  // 8
#define CTL_TIEIDX    256  // 1024
#define CTL_SIZE      1280

__device__ __forceinline__ uint32_t skey(uint32_t b){
  return (b & 0x80000000u) ? ~b : (b | 0x80000000u);   // ascending-sortable
}

// inclusive suffix scan, one segment of width L (L<=8192), block-wide Hillis
__device__ void scan1(uint32_t* a, uint32_t* tmp, int L){
  for (int d = 1; d < L; d <<= 1){
    for (int i = threadIdx.x; i < L; i += blockDim.x)
      tmp[i] = a[i] + ((i + d < L) ? a[i + d] : 0u);
    __syncthreads();
    for (int i = threadIdx.x; i < L; i += blockDim.x) a[i] = tmp[i];
    __syncthreads();
  }
}

// segmented inclusive suffix scan: segments of width 512
__device__ void scan_seg512(uint32_t* a, uint32_t* tmp, int total){
  for (int d = 1; d < 512; d <<= 1){
    for (int i = threadIdx.x; i < total; i += blockDim.x){
      int j = i & 511;
      tmp[i] = a[i] + ((j + d < 512) ? a[i + d] : 0u);
    }
    __syncthreads();
    for (int i = threadIdx.x; i < total; i += blockDim.x) a[i] = tmp[i];
    __syncthreads();
  }
}

// lo = max{ i : suf[i] > R } (virtual suf[L]=0); requires suf[0] > R
__device__ int suf_search(const uint32_t* suf, int L, uint32_t R){
  int lo = 0, hi = L;
  while (hi - lo > 1){
    int mid = (lo + hi) >> 1;
    uint32_t s = (mid < L) ? suf[mid] : 0u;
    if (s > R) lo = mid; else hi = mid;
  }
  return lo;
}

// ---------------- pass 1: coarse 13-bit histogram (LDS, partials) ----------
__global__ __launch_bounds__(1024) void k_hist13(const uint32_t* __restrict__ xb,
    uint32_t* __restrict__ part13, int n4){
  __shared__ uint32_t h[H13BINS];
  int tid = threadIdx.x;
  for (int i = tid; i < H13BINS; i += 1024) h[i] = 0u;
  __syncthreads();
  int T = gridDim.x * blockDim.x;
  int i = blockIdx.x * blockDim.x + tid;
  for (; i + 3 * T < n4; i += 4 * T){
    uint4 a = ((const uint4*)xb)[i];
    uint4 b = ((const uint4*)xb)[i + T];
    uint4 cc = ((const uint4*)xb)[i + 2 * T];
    uint4 d = ((const uint4*)xb)[i + 3 * T];
    uint32_t v[16] = {a.x,a.y,a.z,a.w, b.x,b.y,b.z,b.w,
                      cc.x,cc.y,cc.z,cc.w, d.x,d.y,d.z,d.w};
    #pragma unroll
    for (int j = 0; j < 16; j++) atomicAdd(&h[skey(v[j]) >> 19], 1u);
  }
  for (; i < n4; i += T){
    uint4 a = ((const uint4*)xb)[i];
    atomicAdd(&h[skey(a.x) >> 19], 1u);
    atomicAdd(&h[skey(a.y) >> 19], 1u);
    atomicAdd(&h[skey(a.z) >> 19], 1u);
    atomicAdd(&h[skey(a.w) >> 19], 1u);
  }
  __syncthreads();
  uint32_t* dst = part13 + (size_t)blockIdx.x * H13BINS;
  for (int j = tid; j < H13BINS; j += 1024) dst[j] = h[j];
}

__global__ void k_red13(const uint32_t* __restrict__ part13, uint32_t* __restrict__ H13){
  int b = blockIdx.x * blockDim.x + threadIdx.x;   // 8192 threads
  uint32_t s = 0;
  for (int p = 0; p < P13; p++) s += part13[(size_t)p * H13BINS + b];
  H13[b] = s;
}

// ---------------- single block: select candidate 13-bit bins ---------------
__global__ __launch_bounds__(1024) void k_sel13(const uint32_t* __restrict__ H13,
    uint32_t* __restrict__ ctl, uint8_t* __restrict__ table13,
    uint32_t k, uint32_t c, uint32_t n){
  __shared__ uint32_t sA[8192];
  __shared__ uint32_t sT[8192];
  __shared__ uint32_t sAbs[4096];
  __shared__ uint32_t cBin13[32], cRes[32];
  __shared__ uint32_t shv[4];   // 0:astar13 1:rrA 2:aboveA 3:nS
  int tid = threadIdx.x;

  // Phase A: abs selection at 13-bit level
  for (int a = tid; a < 4096; a += 1024) sAbs[a] = H13[4096 + a] + H13[4095 - a];
  __syncthreads();
  scan1(sAbs, sT, 4096);
  if (tid == 0){
    int astar = suf_search(sAbs, 4096, k - 1u);
    uint32_t aboveA = (astar + 1 < 4096) ? sAbs[astar + 1] : 0u;
    shv[0] = (uint32_t)astar; shv[1] = (k - 1u) - aboveA; shv[2] = aboveA;
  }
  __syncthreads();
  uint32_t astar13 = shv[0];

  // Phase B: signed suffix scan + 32 candidate ranks
  for (int i = tid; i < 8192; i += 1024) sA[i] = H13[i];
  __syncthreads();
  scan1(sA, sT, 8192);
  uint32_t posThr13 = 4096u + astar13;
  if (tid < 32){
    int i = tid & 15;
    uint32_t kr = (i < 8) ? (uint32_t)i * c : (uint32_t)(i - 7) * c - 1u;
    uint32_t Rr = (tid < 16) ? kr : (n - k + kr);
    int q = suf_search(sA, 8192, Rr);
    uint32_t aboveC = (q + 1 < 8192) ? sA[q + 1] : 0u;
    cBin13[tid] = (uint32_t)q;
    cRes[tid] = Rr - aboveC;
  }
  __syncthreads();

  if (tid == 0){
    uint32_t bins[NSLOT_MAX]; int nS = 0;
    bins[nS++] = posThr13;            // slot 0 = pos threshold 13-bin
    bins[nS++] = 4095u - astar13;     // slot 1 = neg threshold 13-bin
    for (int cd = 0; cd < 32; cd++){
      uint32_t b = cBin13[cd]; int s = -1;
      for (int t2 = 0; t2 < nS; t2++) if (bins[t2] == b){ s = t2; break; }
      if (s < 0){ s = nS; bins[nS++] = b; }
      ctl[CTL_C13SLOT + cd] = (uint32_t)s;
      ctl[CTL_C13RES + cd]  = cRes[cd];
    }
    for (int s = 0; s < nS; s++) ctl[CTL_S13BIN + s] = bins[s];
    ctl[CTL_NS13] = (uint32_t)nS;
    ctl[CTL_ASTAR13] = astar13;
    ctl[CTL_RRA] = shv[1];
    ctl[CTL_ABOVEA] = shv[2];
    ctl[CTL_POSAB13] = (posThr13 + 1u < 8192u) ? sA[posThr13 + 1] : 0u;
    shv[3] = (uint32_t)nS;
  }
  __syncthreads();
  // bin13 -> slot+1 lookup table (8192 bytes)
  for (int i = tid; i < 2048; i += 1024) ((uint32_t*)table13)[i] = 0u;
  __syncthreads();
  uint32_t nS = shv[3];
  if (tid < (int)nS) table13[ctl[CTL_S13BIN + tid]] = (uint8_t)(tid + 1);
}

// ---------------- pass 2: refine candidate bins to 22 bits (LDS) -----------
__global__ __launch_bounds__(1024) void k_hist9(const uint32_t* __restrict__ xb,
    const uint8_t* __restrict__ table13, const uint32_t* __restrict__ ctl,
    uint32_t* __restrict__ part9, int n4){
  __shared__ uint8_t tb[H13BINS];
  __shared__ uint32_t fine[NSLOT_MAX * 512];
  __shared__ uint32_t snS;
  int tid = threadIdx.x;
  for (int i = tid; i < 2048; i += 1024) ((uint32_t*)tb)[i] = ((const uint32_t*)table13)[i];
  if (tid == 0) snS = ctl[CTL_NS13];
  __syncthreads();
  int L = (int)snS * 512;
  for (int i = tid; i < L; i += 1024) fine[i] = 0u;
  __syncthreads();
  int T = gridDim.x * blockDim.x;
  int i = blockIdx.x * blockDim.x + tid;
  for (; i + 3 * T < n4; i += 4 * T){
    uint4 a = ((const uint4*)xb)[i];
    uint4 b = ((const uint4*)xb)[i + T];
    uint4 cc = ((const uint4*)xb)[i + 2 * T];
    uint4 d = ((const uint4*)xb)[i + 3 * T];
    uint32_t v[16] = {a.x,a.y,a.z,a.w, b.x,b.y,b.z,b.w,
                      cc.x,cc.y,cc.z,cc.w, d.x,d.y,d.z,d.w};
    uint32_t key[16]; uint8_t s[16];
    #pragma unroll
    for (int j = 0; j < 16; j++) key[j] = skey(v[j]);
    #pragma unroll
    for (int j = 0; j < 16; j++) s[j] = tb[key[j] >> 19];   // independent LDS reads
    #pragma unroll
    for (int j = 0; j < 16; j++)
      if (s[j]) atomicAdd(&fine[((uint32_t)s[j] - 1u) * 512u + ((key[j] >> 10) & 511u)], 1u);
  }
  for (; i < n4; i += T){
    uint4 a = ((const uint4*)xb)[i];
    uint32_t bv[4] = {a.x, a.y, a.z, a.w};
    #pragma unroll
    for (int j = 0; j < 4; j++){
      uint32_t key = skey(bv[j]);
      uint32_t s = tb[key >> 19];
      if (s) atomicAdd(&fine[(s - 1u) * 512u + ((key >> 10) & 511u)], 1u);
    }
  }
  __syncthreads();
  uint32_t* dst = part9 + (size_t)blockIdx.x * (NSLOT_MAX * 512);
  for (int j = tid; j < L; j += 1024) dst[j] = fine[j];
}

__global__ void k_red9(const uint32_t* __restrict__ part9,
    const uint32_t* __restrict__ ctl, uint32_t* __restrict__ H9){
  int L = (int)ctl[CTL_NS13] * 512;
  int b = blockIdx.x * blockDim.x + threadIdx.x;   // NSLOT_MAX*512 threads
  if (b >= L) return;
  uint32_t s = 0;
  for (int p = 0; p < P9; p++) s += part9[(size_t)p * (NSLOT_MAX * 512) + b];
  H9[b] = s;
}

// ---------------- single block: resolve 22-bit gather bins + hash table ----
__global__ __launch_bounds__(1024) void k_sel9(const uint32_t* __restrict__ H9,
    uint32_t* __restrict__ ctl, uint32_t* __restrict__ htabG,
    uint32_t* __restrict__ slotCnt){
  __shared__ uint32_t fine[GSL * 512];
  __shared__ uint32_t tmp[GSL * 512];
  __shared__ uint32_t absF[512], absT[512];
  __shared__ uint32_t s13bin[NSLOT_MAX];
  __shared__ uint32_t cSlot[32], cRes[32], cBin22[32], cRes2[32];
  __shared__ uint32_t htabS[HTAB_SZ];
  __shared__ uint32_t sh[4];  // 0:jstar9 1:rr2 2:cntAbove 3:posAbove
  int tid = threadIdx.x;
  uint32_t nS = ctl[CTL_NS13];
  uint32_t astar13 = ctl[CTL_ASTAR13], rrA = ctl[CTL_RRA], aboveA = ctl[CTL_ABOVEA];
  if (tid < (int)NSLOT_MAX) s13bin[tid] = ctl[CTL_S13BIN + tid];
  if (tid < 32){ cSlot[tid] = ctl[CTL_C13SLOT + tid]; cRes[tid] = ctl[CTL_C13RES + tid]; }
  for (int i = tid; i < HTAB_SZ; i += 1024) htabS[i] = 0u;
  __syncthreads();

  for (uint32_t g0 = 0; g0 < nS; g0 += GSL){
    uint32_t gn = nS - g0; if (gn > GSL) gn = GSL;
    int L = (int)gn * 512;
    for (int i = tid; i < L; i += 1024) fine[i] = H9[g0 * 512u + (uint32_t)i];
    __syncthreads();
    if (g0 == 0){
      // abs refine from raw slot0/slot1 fine hists
      for (int j = tid; j < 512; j += 1024) absF[j] = fine[j] + fine[512 + 511 - j];
      __syncthreads();
      scan1(absF, absT, 512);
      if (tid == 0){
        int j = suf_search(absF, 512, rrA);
        uint32_t ab9 = (j + 1 < 512) ? absF[j + 1] : 0u;
        sh[0] = (uint32_t)j; sh[1] = rrA - ab9; sh[2] = aboveA + ab9;
      }
      __syncthreads();
    }
    scan_seg512(fine, tmp, L);
    if (g0 == 0 && tid == 0){
      uint32_t j = sh[0];
      uint32_t pfa = (j + 1u < 512u) ? fine[j + 1u] : 0u;   // slot0 suffix above jstar9
      sh[3] = ctl[CTL_POSAB13] + pfa;
    }
    if (tid < 32){
      uint32_t s = cSlot[tid];
      if (s >= g0 && s < g0 + gn){
        uint32_t* seg = fine + (s - g0) * 512u;
        int bl = suf_search(seg, 512, cRes[tid]);
        uint32_t ab = (bl + 1 < 512) ? seg[bl + 1] : 0u;
        cBin22[tid] = (s13bin[s] << 9) | (uint32_t)bl;
        cRes2[tid] = cRes[tid] - ab;
      }
    }
    __syncthreads();
  }

  if (tid == 0){
    uint32_t jstar9 = sh[0];
    uint32_t posBin22 = ((4096u + astar13) << 9) | jstar9;
    uint32_t negBin22 = ((4095u - astar13) << 9) | (511u - jstar9);
    uint32_t bins[NSLOT_MAX]; int nG = 0;
    bins[nG++] = posBin22;
    bins[nG++] = negBin22;
    for (int cd = 0; cd < 32; cd++){
      uint32_t b = cBin22[cd]; int s = -1;
      for (int t2 = 0; t2 < nG; t2++) if (bins[t2] == b){ s = t2; break; }
      if (s < 0){ s = nG; bins[nG++] = b; }
      ctl[CTL_CANDSLOT + cd] = (uint32_t)s;
      ctl[CTL_CANDRES + cd]  = cRes2[cd];
    }
    ctl[CTL_NSLOT] = (uint32_t)nG;
    for (int s = 0; s < nG; s++) ctl[CTL_SLOTBIN + s] = bins[s];
    ctl[CTL_RR2] = sh[1];
    ctl[CTL_CNTABOVE] = sh[2];
    ctl[CTL_POSABOVE] = sh[3];
    ctl[CTL_A21] = (astar13 << 9) | jstar9;
    // build gather hash table: entry = (bin22<<8)|(slot+1), 0 = empty
    for (int s = 0; s < nG; s++){
      uint32_t b = bins[s];
      uint32_t h = (b * 2654435761u) >> 21;
      while (htabS[h]) h = (h + 1u) & (HTAB_SZ - 1u);
      htabS[h] = (b << 8) | (uint32_t)(s + 1);
    }
  }
  __syncthreads();
  for (int i = tid; i < HTAB_SZ; i += 1024) htabG[i] = htabS[i];
  if (tid < NSLOT_MAX) slotCnt[tid] = 0u;   // replaces host-side memset
}

// ---------------- pass 3: gather via batched two-phase hash probe ----------
__global__ __launch_bounds__(256) void k_gather(const uint32_t* __restrict__ xb,
    const uint32_t* __restrict__ htabG, uint32_t* __restrict__ slotCnt,
    uint64_t* __restrict__ slotBuf, int n4){
  __shared__ uint32_t htab[HTAB_SZ];
  int tid = threadIdx.x;
  for (int i = tid; i < HTAB_SZ; i += 256) htab[i] = htabG[i];
  __syncthreads();
  int T = gridDim.x * blockDim.x;
  int i = blockIdx.x * blockDim.x + tid;
  for (; i + 3 * T < n4; i += 4 * T){
    uint4 a = ((const uint4*)xb)[i];
    uint4 b = ((const uint4*)xb)[i + T];
    uint4 cc = ((const uint4*)xb)[i + 2 * T];
    uint4 d = ((const uint4*)xb)[i + 3 * T];
    uint32_t key[16] = {a.x,a.y,a.z,a.w, b.x,b.y,b.z,b.w,
                        cc.x,cc.y,cc.z,cc.w, d.x,d.y,d.z,d.w};
    uint32_t hh[16], e[16];
    #pragma unroll
    for (int j = 0; j < 16; j++) key[j] = skey(key[j]);
    #pragma unroll
    for (int j = 0; j < 16; j++) hh[j] = ((key[j] >> 10) * 2654435761u) >> 21;
    #pragma unroll
    for (int j = 0; j < 16; j++) e[j] = htab[hh[j]];   // independent first probes
    #pragma unroll
    for (int j = 0; j < 16; j++){
      if (e[j]){                                        // rare (~1.7%)
        uint32_t bin = key[j] >> 10;
        uint32_t h2 = hh[j], ee = e[j];
        while (true){
          if ((ee >> 8) == bin){
            uint32_t s = (ee & 255u) - 1u;
            uint32_t idx = (uint32_t)(i + (j >> 2) * T) * 4u + (uint32_t)(j & 3);
            uint32_t pos = atomicAdd(&slotCnt[s], 1u);
            if (pos < SLOT_CAP)
              slotBuf[(size_t)s * SLOT_CAP + pos] = ((uint64_t)key[j] << 32) | (uint64_t)idx;
            break;
          }
          h2 = (h2 + 1u) & (HTAB_SZ - 1u);
          ee = htab[h2];
          if (!ee) break;
        }
      }
    }
  }
  for (; i < n4; i += T){
    uint4 v = ((const uint4*)xb)[i];
    uint32_t bv[4] = {v.x, v.y, v.z, v.w};
    uint32_t base = (uint32_t)i * 4u;
    #pragma unroll
    for (int j = 0; j < 4; j++){
      uint32_t key = skey(bv[j]);
      uint32_t bin = key >> 10;
      uint32_t h = (bin * 2654435761u) >> 21;
      while (true){
        uint32_t e = htab[h];
        if (!e) break;
        if ((e >> 8) == bin){
          uint32_t s = (e & 255u) - 1u;
          uint32_t pos = atomicAdd(&slotCnt[s], 1u);
          if (pos < SLOT_CAP)
            slotBuf[(size_t)s * SLOT_CAP + pos] = ((uint64_t)key << 32) | (uint64_t)(base + (uint32_t)j);
          break;
        }
        h = (h + 1u) & (HTAB_SZ - 1u);
      }
    }
  }
}

// ---------------- single block: exact t, ties, num_pos, boundaries ---------
__global__ __launch_bounds__(1024) void k_s2(uint32_t* __restrict__ ctl,
    const uint32_t* __restrict__ slotCnt, const uint64_t* __restrict__ slotBuf,
    uint32_t k, uint32_t c){
  __shared__ uint32_t sH[1024];
  __shared__ uint32_t sS[1024];
  __shared__ uint32_t sT[1024];
  __shared__ uint32_t red[1024];
  __shared__ uint32_t bHist[16 * 1024];     // per-wave boundary histograms
  __shared__ uint32_t tieIdx[MAX_TIES];
  __shared__ uint8_t  tieSgn[MAX_TIES];
  __shared__ uint32_t sCnt[4];
  __shared__ uint32_t tvU[16];
  int tid = threadIdx.x;
  uint32_t a21 = ctl[CTL_A21], rr2 = ctl[CTL_RR2], cntAbove = ctl[CTL_CNTABOVE];
  uint32_t cntP = slotCnt[0]; if (cntP > SLOT_CAP) cntP = SLOT_CAP;
  uint32_t cntN = slotCnt[1]; if (cntN > SLOT_CAP) cntN = SLOT_CAP;

  // resolve low 10 bits of |t|
  for (int j = tid; j < 1024; j += 1024) sH[j] = 0u;
  __syncthreads();
  for (uint32_t e = tid; e < cntP; e += 1024){
    uint32_t key = (uint32_t)(slotBuf[e] >> 32);
    atomicAdd(&sH[key & 1023u], 1u);
  }
  for (uint32_t e = tid; e < cntN; e += 1024){
    uint32_t key = (uint32_t)(slotBuf[SLOT_CAP + e] >> 32);
    uint32_t m = 0x7FFFFFFFu - key;
    atomicAdd(&sH[m & 1023u], 1u);
  }
  __syncthreads();
  for (int j = tid; j < 1024; j += 1024) sS[j] = sH[j];
  __syncthreads();
  scan1(sS, sT, 1024);
  int l = suf_search(sS, 1024, rr2);
  uint32_t w = (l + 1 < 1024) ? sS[l + 1] : 0u;
  uint32_t cnt_gt = cntAbove + w;
  uint32_t r_ties = k - cnt_gt;
  uint32_t t_key = (a21 << 10) | (uint32_t)l;

  // collect ties, keep r_ties smallest flat indices (stable, as jax top_k)
  if (tid == 0){ sCnt[0] = 0u; sCnt[1] = 0u; sCnt[2] = 0u; }
  __syncthreads();
  for (uint32_t e = tid; e < cntP; e += 1024){
    uint64_t ent = slotBuf[e];
    uint32_t key = (uint32_t)(ent >> 32);
    if ((key & 1023u) == (uint32_t)l){
      uint32_t p = atomicAdd(&sCnt[0], 1u);
      if (p < MAX_TIES){ tieIdx[p] = (uint32_t)ent; tieSgn[p] = 1; }
    }
  }
  for (uint32_t e = tid; e < cntN; e += 1024){
    uint64_t ent = slotBuf[SLOT_CAP + e];
    uint32_t key = (uint32_t)(ent >> 32);
    uint32_t m = 0x7FFFFFFFu - key;
    if ((m & 1023u) == (uint32_t)l){
      uint32_t p = atomicAdd(&sCnt[0], 1u);
      if (p < MAX_TIES){ tieIdx[p] = (uint32_t)ent; tieSgn[p] = 0; }
    }
  }
  __syncthreads();
  uint32_t mT = sCnt[0]; if (mT > MAX_TIES) mT = MAX_TIES;
  for (uint32_t e = tid; e < mT; e += 1024){
    uint32_t my = tieIdx[e];
    uint32_t rank = 0;
    for (uint32_t f = 0; f < mT; f++) rank += (tieIdx[f] < my) ? 1u : 0u;
    if (rank < r_ties){
      uint32_t p = atomicAdd(&sCnt[1], 1u);
      if (p < MAX_TIES) ctl[CTL_TIEIDX + p] = my;
      if (tieSgn[e]) atomicAdd(&sCnt[2], 1u);
    }
  }
  __syncthreads();
  uint32_t nSel = sCnt[1]; if (nSel > MAX_TIES) nSel = MAX_TIES;
  uint32_t selPos = sCnt[2];

  // num_pos = #{x > |t|} + selected positive ties
  uint32_t part = 0;
  for (uint32_t e = tid; e < cntP; e += 1024){
    uint32_t key = (uint32_t)(slotBuf[e] >> 32);
    if ((key & 1023u) > (uint32_t)l) part++;
  }
  red[tid] = part;
  __syncthreads();
  for (int o = 512; o; o >>= 1){ if (tid < o) red[tid] += red[tid + o]; __syncthreads(); }
  uint32_t num_pos = red[0] + ctl[CTL_POSABOVE] + selPos;
  __syncthreads();

  // resolve 16 boundary values in parallel: wave wv handles boundary wv
  // (mx_p = kept rank p*c for wv<8; mn_{wv-8} = kept rank (wv-7)*c-1)
  {
    int wv = tid >> 6, ln = tid & 63;
    uint32_t kr = (wv < 8) ? (uint32_t)wv * c : (uint32_t)(wv - 7) * c - 1u;
    int cand = (kr < num_pos) ? wv : (16 + wv);
    uint32_t slot  = ctl[CTL_CANDSLOT + cand];
    uint32_t resid = ctl[CTL_CANDRES + cand];
    uint32_t bin   = ctl[CTL_SLOTBIN + slot];
    uint32_t cnt2  = slotCnt[slot]; if (cnt2 > SLOT_CAP) cnt2 = SLOT_CAP;
    uint32_t* h = bHist + wv * 1024;
    for (int j = ln; j < 1024; j += 64) h[j] = 0u;
    __syncthreads();
    for (uint32_t e = ln; e < cnt2; e += 64){
      uint32_t key = (uint32_t)(slotBuf[(size_t)slot * SLOT_CAP + e] >> 32);
      atomicAdd(&h[key & 1023u], 1u);
    }
    __syncthreads();
    // lane-local suffix over bins [ln*16, ln*16+16)
    uint32_t loc[16]; uint32_t lsuf = 0;
    #pragma unroll
    for (int j = 15; j >= 0; j--){ lsuf += h[ln * 16 + j]; loc[j] = lsuf; }
    uint32_t T = lsuf;
    uint32_t S = T;                       // inclusive suffix across lanes
    #pragma unroll
    for (int off = 1; off < 64; off <<= 1){
      uint32_t t2 = __shfl_down(S, off);
      if (ln + off < 64) S += t2;
    }
    uint32_t excl = S - T;                // sum over lanes > ln
    bool cross = (S > resid) && (excl <= resid);
    if (cross){
      int bl = 0;
      #pragma unroll
      for (int j = 15; j >= 0; j--){
        if (excl + loc[j] > resid){ bl = j; break; }
      }
      uint32_t fullkey = (bin << 10) | (uint32_t)(ln * 16 + bl);
      uint32_t bits = (fullkey & 0x80000000u) ? (fullkey ^ 0x80000000u) : ~fullkey;
      tvU[wv] = bits;
    }
  }
  __syncthreads();

  if (tid == 0){
    ctl[CTL_TKEY] = t_key;
    ctl[CTL_NTIES] = nSel;
    for (int j = 1; j < 8; j++) ctl[CTL_BND + (j - 1)] = tvU[j];   // b_j = mx_j
    for (int p = 0; p < 8; p++){
      float mx = __uint_as_float(tvU[p]), mn = __uint_as_float(tvU[8 + p]);
      ctl[CTL_MN + p] = tvU[8 + p];
      ctl[CTL_MX + p] = tvU[p];
      ctl[CTL_STEP + p] = __float_as_uint((mx - mn) / 255.0f);
    }
  }
}

// ---------------- pass 4: write quantized output ---------------------------
struct QP { float b[7], mn[8], mx[8], st[8]; uint32_t tk, nt; };

__device__ __forceinline__ float4 quant4(uint4 v, uint32_t base,
    const QP& qp, const uint32_t* sTie){
  uint32_t bv[4] = {v.x, v.y, v.z, v.w};
  float ov[4];
  #pragma unroll
  for (int j = 0; j < 4; j++){
    uint32_t b = bv[j];
    uint32_t m = b & 0x7FFFFFFFu;
    float q = 0.0f;
    bool keep = m > qp.tk;
    if (m == qp.tk){
      uint32_t idx = base + (uint32_t)j;
      for (uint32_t e = 0; e < qp.nt; e++) if (sTie[e] == idx){ keep = true; break; }
    }
    if (keep){
      float x = __uint_as_float(b);
      int p = 0;
      #pragma unroll
      for (int j2 = 0; j2 < 7; j2++) p += (qp.b[j2] >= x) ? 1 : 0;
      float mn = qp.mn[p], mx = qp.mx[p], st = qp.st[p];
      if (mn == mx) q = x;
      else {
        float sst = (st == 0.0f) ? 1.0f : st;
        q = rintf((x - mn) / sst) * st + mn;
      }
    }
    ov[j] = q;
  }
  return make_float4(ov[0], ov[1], ov[2], ov[3]);
}

__global__ __launch_bounds__(256) void k_out(const uint32_t* __restrict__ xb,
    float* __restrict__ out, const uint32_t* __restrict__ ctl, int n4){
  __shared__ uint32_t sTie[MAX_TIES];
  __shared__ QP qp;
  int tid = threadIdx.x;
  if (tid == 0){ qp.tk = ctl[CTL_TKEY]; qp.nt = ctl[CTL_NTIES]; }
  if (tid < 7) qp.b[tid] = __uint_as_float(ctl[CTL_BND + tid]);
  if (tid >= 8 && tid < 16) qp.mn[tid - 8] = __uint_as_float(ctl[CTL_MN + tid - 8]);
  if (tid >= 16 && tid < 24) qp.mx[tid - 16] = __uint_as_float(ctl[CTL_MX + tid - 16]);
  if (tid >= 24 && tid < 32) qp.st[tid - 24] = __uint_as_float(ctl[CTL_STEP + tid - 24]);
  __syncthreads();
  for (int e = tid; e < (int)qp.nt; e += blockDim.x) sTie[e] = ctl[CTL_TIEIDX + e];
  __syncthreads();
  int T = gridDim.x * blockDim.x;
  int i = blockIdx.x * blockDim.x + tid;
  for (; i + 3 * T < n4; i += 4 * T){
    uint4 a = ((const uint4*)xb)[i];
    uint4 b = ((const uint4*)xb)[i + T];
    uint4 cc = ((const uint4*)xb)[i + 2 * T];
    uint4 d = ((const uint4*)xb)[i + 3 * T];
    ((float4*)out)[i]         = quant4(a, (uint32_t)i * 4u, qp, sTie);
    ((float4*)out)[i + T]     = quant4(b, (uint32_t)(i + T) * 4u, qp, sTie);
    ((float4*)out)[i + 2 * T] = quant4(cc, (uint32_t)(i + 2 * T) * 4u, qp, sTie);
    ((float4*)out)[i + 3 * T] = quant4(d, (uint32_t)(i + 3 * T) * 4u, qp, sTie);
  }
  for (; i < n4; i += T){
    uint4 v = ((const uint4*)xb)[i];
    ((float4*)out)[i] = quant4(v, (uint32_t)i * 4u, qp, sTie);
  }
}

// ---------------------------------------------------------------------------
extern "C" void kernel_launch(void* const* d_in, const int* in_sizes, int n_in,
                              void* d_out, int out_size, void* d_ws, size_t ws_size,
                              hipStream_t stream){
  const uint32_t* xb = (const uint32_t*)d_in[0];
  float* out = (float*)d_out;
  uint32_t n = (uint32_t)in_sizes[0];
  uint32_t k = n / 4u;
  uint32_t c = k / 8u;

  // ws layout (u32 units)
  uint32_t* w = (uint32_t*)d_ws;
  uint32_t* H13     = w;                            // 8192
  uint32_t* H9      = H13 + H13BINS;                // 40*512 = 20480
  uint8_t*  table13 = (uint8_t*)(H9 + NSLOT_MAX*512); // 8192 B (2048 u32)
  uint32_t* ctl     = (uint32_t*)(table13 + H13BINS); // 1280
  uint32_t* htabG   = ctl + CTL_SIZE;               // 2048
  uint32_t* slotCnt = htabG + HTAB_SZ;              // 40
  uint64_t* slotBuf = (uint64_t*)(slotCnt + NSLOT_MAX); // 40*8192 u64
  uint32_t* part13  = (uint32_t*)(slotBuf + (size_t)NSLOT_MAX * SLOT_CAP);
  uint32_t* part9   = part13 + (size_t)P13 * H13BINS;
  size_t endu32 = (size_t)((uint32_t*)part9 - w) + (size_t)P9 * NSLOT_MAX * 512;
  if (ws_size < endu32 * 4u){
    hipMemsetAsync(d_out, 0, (size_t)out_size * 4u, stream);
    return;
  }

  int n4 = (int)(n / 4u);
  k_hist13<<<P13, 1024, 0, stream>>>(xb, part13, n4);
  k_red13 <<<H13BINS / 256, 256, 0, stream>>>(part13, H13);
  k_sel13 <<<1, 1024, 0, stream>>>(H13, ctl, table13, k, c, n);
  k_hist9 <<<P9, 1024, 0, stream>>>(xb, table13, ctl, part9, n4);
  k_red9  <<<(NSLOT_MAX * 512) / 256, 256, 0, stream>>>(part9, ctl, H9);
  k_sel9  <<<1, 1024, 0, stream>>>(H9, ctl, htabG, slotCnt);
  k_gather<<<GATHER_BLOCKS, 256, 0, stream>>>(xb, htabG, slotCnt, slotBuf, n4);
  k_s2    <<<1, 1024, 0, stream>>>(ctl, slotCnt, slotBuf, k, c);
  k_out   <<<OUT_BLOCKS, 256, 0, stream>>>(xb, out, ctl, n4);
}